// Round 14
// baseline (105.715 us; speedup 1.0000x reference)
//
#include <hip/hip_runtime.h>

#define B 64
#define N 1024
#define E 16384
#define WPR 32          // words per adjacency row = N/32
#define NITER 5
#define CSR_SLOTS (E + N)   // even-aligned per-node alloc: <=1 pad slot/node
#define MAXP 20             // pair-words cached in registers (deg<=40; LDS fallback beyond)
#define SENT_PAIR 0x04000400u   // (N<<16)|N : both halves index s_lab[N]==0
#define CAP 8               // grp2 slots per bucket (overflow -> slow path)
#define GSTRIDE 9           // grp2 row stride (9 coprime 32 => bank-conflict-free)

// ---- workspace layout (bytes) ---- (NO memset: feats/diag fully stored
// before any read; harness 0xAA poison harmless)
#define FEATS_OFF 0
#define DIAG_OFF  ((size_t)B * N * 4)

// R35: scale-reuse. After iter 1 labels are dense ranks [0,1024) -> the
// hash distribution of iters 2-4 matches iter 1's. Reuse iter-1's
// (fmn,scale): bucket = clamp((int)((h-fmn)*scale),0,1023) stays MONOTONE
// (trunc+clamp monotone, block-uniform consts) which is all correctness
// needs; poor spread only raises CAP-overflow probability -> exact slow
// path absorbs it. Iters 2-4: 3 barriers (B1 + minmax DPP + combine gone).
// Base = R34 (R32 4-barrier Phase B + C3 deleted; clock-normalized best
// family). Pre-commit: if |delta| < 1.5us normalized, next round declares
// the ceiling (remaining ideas all <1us vs +-2-3us noise).
__device__ __forceinline__ int dpp_scan_add(int x) {    // 64-lane inclusive sum
    x += __builtin_amdgcn_update_dpp(0, x, 0x111, 0xf, 0xf, true); // row_shr:1
    x += __builtin_amdgcn_update_dpp(0, x, 0x112, 0xf, 0xf, true); // row_shr:2
    x += __builtin_amdgcn_update_dpp(0, x, 0x114, 0xf, 0xf, true); // row_shr:4
    x += __builtin_amdgcn_update_dpp(0, x, 0x118, 0xf, 0xf, true); // row_shr:8
    x += __builtin_amdgcn_update_dpp(0, x, 0x142, 0xa, 0xf, true); // bcast15 -> rows 1,3
    x += __builtin_amdgcn_update_dpp(0, x, 0x143, 0xc, 0xf, true); // bcast31 -> rows 2,3
    return x;                                            // lane63 = total
}
__device__ __forceinline__ unsigned dpp_scan_maxu(unsigned x) { // lane63 = wave max
    unsigned y;
    y = (unsigned)__builtin_amdgcn_update_dpp(0, (int)x, 0x111, 0xf, 0xf, true); x = x > y ? x : y;
    y = (unsigned)__builtin_amdgcn_update_dpp(0, (int)x, 0x112, 0xf, 0xf, true); x = x > y ? x : y;
    y = (unsigned)__builtin_amdgcn_update_dpp(0, (int)x, 0x114, 0xf, 0xf, true); x = x > y ? x : y;
    y = (unsigned)__builtin_amdgcn_update_dpp(0, (int)x, 0x118, 0xf, 0xf, true); x = x > y ? x : y;
    y = (unsigned)__builtin_amdgcn_update_dpp(0, (int)x, 0x142, 0xa, 0xf, true); x = x > y ? x : y;
    y = (unsigned)__builtin_amdgcn_update_dpp(0, (int)x, 0x143, 0xc, 0xf, true); x = x > y ? x : y;
    return x;
}
__device__ __forceinline__ int dpp_red16_add(int x) {   // every lane: sum of its 16-group
    x += __builtin_amdgcn_update_dpp(0, x, 0xB1, 0xf, 0xf, true);  // quad_perm [1,0,3,2]
    x += __builtin_amdgcn_update_dpp(0, x, 0x4E, 0xf, 0xf, true);  // quad_perm [2,3,0,1]
    x += __builtin_amdgcn_update_dpp(0, x, 0x141, 0xf, 0xf, true); // row_half_mirror
    x += __builtin_amdgcn_update_dpp(0, x, 0x140, 0xf, 0xf, true); // row_mirror
    return x;
}
__device__ __forceinline__ unsigned dpp_red16_maxu(unsigned x) {
    unsigned y;
    y = (unsigned)__builtin_amdgcn_update_dpp(0, (int)x, 0xB1, 0xf, 0xf, true);  x = x > y ? x : y;
    y = (unsigned)__builtin_amdgcn_update_dpp(0, (int)x, 0x4E, 0xf, 0xf, true);  x = x > y ? x : y;
    y = (unsigned)__builtin_amdgcn_update_dpp(0, (int)x, 0x141, 0xf, 0xf, true); x = x > y ? x : y;
    y = (unsigned)__builtin_amdgcn_update_dpp(0, (int)x, 0x140, 0xf, 0xf, true); x = x > y ? x : y;
    return x;
}
// monotone float<->uint total-order keys (no NaNs in this kernel)
__device__ __forceinline__ unsigned fkey(float h) {
    unsigned s = __float_as_uint(h);
    return ((int)s < 0) ? ~s : (s | 0x80000000u);
}
__device__ __forceinline__ float ubf(unsigned u) {
    unsigned s = (u & 0x80000000u) ? (u & 0x7FFFFFFFu) : ~u;
    return __uint_as_float(s);
}

__global__ void __launch_bounds__(1024) wl_mega_k(const int* __restrict__ src,
                                                  const int* __restrict__ dstp,
                                                  const int* __restrict__ lab0,
                                                  const float* __restrict__ hw,
                                                  unsigned int* __restrict__ feats,
                                                  float* __restrict__ diag) {
    __shared__ union {
        unsigned int chunk[N * WPR];                // Phase A1: 128KB full bitmask
        struct {
            unsigned short nbr[CSR_SLOTS];          // Phase A2/B: 34816B CSR (self-read only)
            struct {                                // Phase B: rank arrays
                int hist[N];
                int scan[N];
                float grp[N];                       // slow-path ordered groups
                int flag[N];
                float grp2[N * GSTRIDE];            // fast-path groups, 36KB
            } pb;
        } s;
    } u;
    __shared__ int s_lab[N + 2];                    // +sentinel slot (=0)
    __shared__ unsigned int s_feats[N];
    __shared__ int s_wsum[16];
    __shared__ int s_kp[16];
    __shared__ unsigned long long s_mm64[16];       // packed (maxkey<<32)|minkey
    __shared__ int s_anytie;
    __shared__ int s_ovf;
    int b = blockIdx.x, t = threadIdx.x;
    int lane = t & 63, w = t >> 6;

    // ---- Phase A0: edge loads first (L3 latency overlaps LDS zero) ----
    const int* sg = src + (size_t)b * E;
    const int* dg_ = dstp + (size_t)b * E;
    int es[16], ed[16];
#pragma unroll
    for (int k = 0; k < 16; ++k) {                  // coalesced, 1 block/graph
        es[k] = sg[t + k * 1024];
        ed[k] = dg_[t + k * 1024];
    }
    int l0 = lab0[(size_t)b * N + t];
    float w0 = hw[0], w1 = hw[1];
    // zero 128KB bitmask while loads are in flight
#pragma unroll
    for (int k = 0; k < 8; ++k)
        ((uint4*)u.chunk)[t + k * 1024] = make_uint4(0, 0, 0, 0);
    s_lab[t] = l0;
    s_feats[t] = 0;
    if (t == 0) { s_lab[N] = 0; s_anytie = 0; s_ovf = 0; }
    __syncthreads();                                        // P0
    // init label bincount (labels < 16) via ballot
#pragma unroll
    for (int v = 0; v < 16; ++v) {
        unsigned long long m = __ballot(l0 == v);
        if (lane == v) {
            int c = __popcll(m);
            if (c) atomicAdd(&s_feats[v], (unsigned)c);
        }
    }

    // ---- Phase A1: bitmask scatter (swizzled), row -> r[8] ----
#pragma unroll
    for (int k = 0; k < 16; ++k) {
        int wlog = ed[k] >> 5;                      // logical word 0..31
        int g = wlog >> 2;                          // logical group 0..7
        int p = (g + es[k]) & 7;                    // swizzled slot
        atomicOr(&u.chunk[es[k] * WPR + p * 4 + (wlog & 3)], 1u << (ed[k] & 31));
    }
    __syncthreads();                                        // C2
    uint4 r[8];
    {
        const uint4* row4 = (const uint4*)(u.chunk + t * WPR);
#pragma unroll
        for (int g = 0; g < 8; ++g)
            r[g] = row4[(g + t) & 7];               // conflict-free (swizzled)
    }
    // NO C3: A1 (below) already separates this readback from the chunk-
    // aliasing writes (hist/flag init + pack); the window here touches only
    // registers and s_wsum/s_kp (outside the union).

    // ---- Phase A2: deg/alloc/K/CSR starts + pack ----
    int dg = 0;
#pragma unroll
    for (int k = 0; k < 8; ++k)
        dg += __popc(r[k].x) + __popc(r[k].y) + __popc(r[k].z) + __popc(r[k].w);
    int alloc = (dg + 1) & ~1;                      // even per-node CSR alloc

    int f = dpp_scan_add(alloc);                    // wave inclusive scan (VALU)
    unsigned kmw = dpp_scan_maxu((unsigned)dg);     // wave max deg (VALU)
    if (lane == 63) { s_wsum[w] = f; s_kp[w] = (int)kmw; }
    __syncthreads();                                        // A1
    // all-wave redundant combine: wave-exclusive base + block K, in registers
    float Kf;
    int start;
    {
        int vv = ((lane & 15) < w) ? s_wsum[lane & 15] : 0;
        vv = dpp_red16_add(vv);
        start = (f - alloc) + vv;                   // even => u32-aligned
        unsigned kk = dpp_red16_maxu((unsigned)s_kp[lane & 15]);
        Kf = (float)kk;
    }
    u.s.pb.hist[t] = 0;                             // aliases chunk: re-init
    u.s.pb.flag[t] = 0;

    // pack own row's set bits ONCE -> u16 list; pad odd deg with sentinel N
    {
        int idx = start;
#pragma unroll
        for (int k = 0; k < 8; ++k) {
            unsigned int wv[4] = { r[k].x, r[k].y, r[k].z, r[k].w };
#pragma unroll
            for (int c2 = 0; c2 < 4; ++c2) {
                unsigned int word = wv[c2];
                int bb = (k * 4 + c2) << 5;
                while (word) {
                    int j = __ffs(word) - 1;
                    word &= word - 1;
                    u.s.nbr[idx++] = (unsigned short)(bb + j);
                }
            }
        }
        if (dg & 1) u.s.nbr[idx] = (unsigned short)N;   // sentinel -> adds 0
    }
    // NO barrier: pw preload reads only this thread's own nbr bytes (same-
    // wave DS ops are serviced in order); fence stops compiler reordering.
    asm volatile("" ::: "memory");

    int vdeg = dg;
    int vpstart = start >> 1;
    int vpairs = alloc >> 1;
    int lab_reg = l0;
    const unsigned int* nbr32 = (const unsigned int*)u.s.nbr;
    // iteration-invariant pair-words -> registers; sentinel-pad to MAXP so
    // the hot loop needs NO predication (sentinel reads broadcast s_lab[N]=0)
    unsigned int pw[MAXP];
#pragma unroll
    for (int k = 0; k < MAXP; ++k)
        pw[k] = (k < vpairs) ? nbr32[vpstart + k] : SENT_PAIR;

    // ---- Phase B: 5 WL iterations ----
    int nfast = 0;                                  // fast-path feats counter
    float fmn_c = 0.f, scale_c = 0.f;               // iter-1 cached bucket map
    for (int it = 0; it < NITER; ++it) {
        int ssum = 0;
#pragma unroll
        for (int k = 0; k < MAXP; ++k) {            // unconditional: 40 gathers
            unsigned int pr = pw[k];
            ssum += s_lab[pr & 0xFFFFu] + s_lab[pr >> 16];
        }
        for (int k = MAXP; k < vpairs; ++k) {       // rare high-deg fallback
            unsigned int pr = nbr32[vpstart + k];
            ssum += s_lab[pr & 0xFFFFu] + s_lab[pr >> 16];
        }
        float t1 = __fmul_rn(__fmul_rn(Kf, w0), (float)lab_reg);
        float t2 = __fmul_rn(w1, __fsub_rn(__fadd_rn((float)ssum, (float)vdeg), Kf));
        float h  = __fadd_rn(t1, t2);

        float fmn, scale;
        if (it < 2) {
            // wave min/max via DPP max-scan on biased keys (VALU, no DS)
            unsigned uk = fkey(h);
            unsigned kx = dpp_scan_maxu(uk);
            unsigned kn = dpp_scan_maxu(~uk);
            if (lane == 63)
                s_mm64[w] = ((unsigned long long)kx << 32) | kn;  // one b64 store
            __syncthreads();                                // B1 (iters 0,1 only)
            // all-wave redundant combine -> registers (one b64 load)
            unsigned long long mm = s_mm64[lane & 15];
            unsigned a = dpp_red16_maxu((unsigned)mm);      // max of ~key = min
            unsigned cx = dpp_red16_maxu((unsigned)(mm >> 32));
            fmn = ubf(~a);
            float span = ubf(cx) - fmn;
            scale = (span > 0.f) ? (1023.0f / span) : 0.f;
            if (it == 1) { fmn_c = fmn; scale_c = scale; }  // cache for 2-4
        } else {
            // iters 2-4: labels are dense ranks -> distribution matches
            // iter 1; reuse its map. Monotone (trunc+clamp); spread-only
            // risk absorbed by CAP-overflow slow path. NO B1 barrier.
            fmn = fmn_c;
            scale = scale_c;
        }
        int bucket = max(min((int)((h - fmn) * scale), 1023), 0);  // monotone
        int off_in = atomicAdd(&u.s.pb.hist[bucket], 1);
        if (off_in < CAP) u.s.pb.grp2[bucket * GSTRIDE + off_in] = h; // B3 covers
        else s_ovf = 1;                                               // rare
        __syncthreads();                                    // B3

        int ovf = s_ovf;                            // uniform post-B3
        int cnt = u.s.pb.hist[bucket];              // final bucket count (reg)
        int c_in = 0, eq = 0;
        if (!ovf) {                                 // CAP unconditional reads,
#pragma unroll                                      // predicated compares
            for (int j = 0; j < CAP; ++j) {
                float g = u.s.pb.grp2[bucket * GSTRIDE + j];
                if (j < cnt) { c_in += (g < h); eq += (g == h); }
            }
        }
        f = dpp_scan_add(u.s.pb.hist[t]);           // WAVE-inclusive scan
        u.s.pb.scan[t] = f;                         // lane63 entries = wave totals
        __syncthreads();                                    // B4' (merged B4+B6)

        // block-inclusive at bucket: scan[bucket] + prefix of wave totals
        int sb = u.s.pb.scan[bucket];
        {
            int wb = bucket >> 6;
#pragma unroll
            for (int w2 = 0; w2 < 15; ++w2) {       // broadcast reads (same addr)
                int wt = u.s.pb.scan[w2 * 64 + 63];
                if (w2 < wb) sb += wt;
            }
        }
        u.s.pb.hist[t] = 0;             // post-B4': ordered vs cnt latches
        if (t == 0) s_ovf = 0;          // post-B4': ordered vs ovf latches
        int cr;
        if (!ovf) {
            cr = (sb - cnt) + c_in;     // dense rank iff no ties
        } else {                        // slow path: scan-ordered groups
            int bs = sb - cnt;
            u.s.pb.grp[bs + off_in] = h;
            __syncthreads();                                // B7 (rare)
            cr = bs;
            eq = 0;
            for (int k = bs; k < bs + cnt; ++k) {
                float g = u.s.pb.grp[k];
                cr += (g < h);
                eq += (g == h);
            }
        }
        if (eq > 1) s_anytie = it + 1;  // sentinel: stale iters self-invalidate
        s_lab[t] = cr;                  // optimistic fast-path rank
        __syncthreads();                                    // B9
        if (s_anytie == it + 1) {       // rare: dense-rank repair pass
            u.s.pb.flag[cr] = 1;        // class start (same class -> same cr)
            __syncthreads();                                // T1
            int f2 = dpp_scan_add(u.s.pb.flag[t]);  // WAVE-inclusive
            u.s.pb.scan[t] = f2;
            __syncthreads();                                // T2 (merged)
            int sc = u.s.pb.scan[cr];
            {
                int wb2 = cr >> 6;
#pragma unroll
                for (int w2 = 0; w2 < 15; ++w2) {
                    int wt = u.s.pb.scan[w2 * 64 + 63];
                    if (w2 < wb2) sc += wt;
                }
            }
            u.s.pb.flag[t] = 0;         // own flag consumed pre-T2
            int rank = sc - 1;
            s_lab[t] = rank;
            lab_reg = rank;
            atomicAdd(&s_feats[rank], 1u);
            __syncthreads();                                // T5: labels visible
        } else {
            lab_reg = cr;
            ++nfast;                    // permutation => every bin +1
        }
    }

    // ---- Phase C: feats out + fused diag[b] (int exact) ----
    unsigned int fv = s_feats[t] + (unsigned)nfast;
    feats[(size_t)b * N + t] = fv;
    int sq = dpp_scan_add((int)(fv * fv));
    if (lane == 63) s_wsum[w] = sq;
    __syncthreads();
    if (t == 0) {
        int tot = 0;
#pragma unroll
        for (int k = 0; k < 16; ++k) tot += s_wsum[k];
        diag[b] = (float)tot;
    }
}

// gram+normalize fused: one block per row i; f_i staged in LDS; int dots
// exact. 1024 threads, 16 waves x 4 j's each; DPP scan-sum, lane63 stores.
__global__ void __launch_bounds__(1024) gram_k(const unsigned int* __restrict__ feats,
                                               const float* __restrict__ diag,
                                               float* __restrict__ out) {
    __shared__ unsigned int s_fi[N];
    int i = blockIdx.x, t = threadIdx.x;
    int lane = t & 63, w = t >> 6;
    if (t < 256)
        ((uint4*)s_fi)[t] = ((const uint4*)(feats + (size_t)i * N))[t];
    __syncthreads();
    float di = diag[i];
#pragma unroll
    for (int jj = 0; jj < 4; ++jj) {
        int j = w * 4 + jj;
        const uint4* fj = (const uint4*)(feats + (size_t)j * N);
        const uint4* fi = (const uint4*)s_fi;
        int s = 0;
#pragma unroll
        for (int k = 0; k < 4; ++k) {
            uint4 vb = fj[lane + k * 64];
            uint4 va = fi[lane + k * 64];
            s += (int)(va.x * vb.x) + (int)(va.y * vb.y)
               + (int)(va.z * vb.z) + (int)(va.w * vb.w);
        }
        s = dpp_scan_add(s);
        if (lane == 63) out[i * B + j] = (float)s / sqrtf(di * diag[j]);
    }
}

extern "C" void kernel_launch(void* const* d_in, const int* in_sizes, int n_in,
                              void* d_out, int out_size, void* d_ws, size_t ws_size,
                              hipStream_t stream) {
    const int*   esrc = (const int*)d_in[0];
    const int*   edst = (const int*)d_in[1];
    const int*   lab0 = (const int*)d_in[2];
    const float* hw   = (const float*)d_in[3];

    char* ws = (char*)d_ws;
    unsigned int* feats = (unsigned int*)(ws + FEATS_OFF);
    float*        diag  = (float*)(ws + DIAG_OFF);

    wl_mega_k<<<B, 1024, 0, stream>>>(esrc, edst, lab0, hw, feats, diag);
    gram_k<<<B, 1024, 0, stream>>>(feats, diag, (float*)d_out);
}

// Round 15
// 92.794 us; speedup vs baseline: 1.1392x; 1.1392x over previous
//
#include <hip/hip_runtime.h>

#define B 64
#define N 1024
#define E 16384
#define WPR 32          // words per adjacency row = N/32
#define NITER 5
#define CSR_SLOTS (E + N)   // even-aligned per-node alloc: <=1 pad slot/node
#define MAXP 20             // pair-words cached in registers (deg<=40; LDS fallback beyond)
#define SENT_PAIR 0x04000400u   // (N<<16)|N : both halves index s_lab[N]==0
#define CAP 8               // grp2 slots per bucket (overflow -> slow path)
#define GSTRIDE 9           // grp2 row stride (9 coprime 32 => bank-conflict-free)

// ---- workspace layout (bytes) ---- (NO memset: feats/diag fully stored
// before any read; harness 0xAA poison harmless)
#define FEATS_OFF 0
#define DIAG_OFF  ((size_t)B * N * 4)

// R36 = R34 restored (verified best family; clock-normalized dur/fill
// 2.22-2.26). R35's scale-reuse REVERTED: reusing iter-1's (fmn,scale)
// clamps iters 2-4 tails -> crowded buckets -> CAP overflow -> block-wide
// slow path every iter (wl_mega 40->43.4us, VALUBusy 7->11.5%). The
// adaptive per-iter minmax is what keeps buckets ~Poisson(1) and the
// 4-barrier fast path live. Structure: P0/C2/A1 Phase A (C3 deleted),
// B1/B3/B4'/B9 Phase B, DPP scans/reduces (VALU, not ds_bpermute),
// stride-9 grp2 fixed-slot groups, optimistic rank + tie repair.
__device__ __forceinline__ int dpp_scan_add(int x) {    // 64-lane inclusive sum
    x += __builtin_amdgcn_update_dpp(0, x, 0x111, 0xf, 0xf, true); // row_shr:1
    x += __builtin_amdgcn_update_dpp(0, x, 0x112, 0xf, 0xf, true); // row_shr:2
    x += __builtin_amdgcn_update_dpp(0, x, 0x114, 0xf, 0xf, true); // row_shr:4
    x += __builtin_amdgcn_update_dpp(0, x, 0x118, 0xf, 0xf, true); // row_shr:8
    x += __builtin_amdgcn_update_dpp(0, x, 0x142, 0xa, 0xf, true); // bcast15 -> rows 1,3
    x += __builtin_amdgcn_update_dpp(0, x, 0x143, 0xc, 0xf, true); // bcast31 -> rows 2,3
    return x;                                            // lane63 = total
}
__device__ __forceinline__ unsigned dpp_scan_maxu(unsigned x) { // lane63 = wave max
    unsigned y;
    y = (unsigned)__builtin_amdgcn_update_dpp(0, (int)x, 0x111, 0xf, 0xf, true); x = x > y ? x : y;
    y = (unsigned)__builtin_amdgcn_update_dpp(0, (int)x, 0x112, 0xf, 0xf, true); x = x > y ? x : y;
    y = (unsigned)__builtin_amdgcn_update_dpp(0, (int)x, 0x114, 0xf, 0xf, true); x = x > y ? x : y;
    y = (unsigned)__builtin_amdgcn_update_dpp(0, (int)x, 0x118, 0xf, 0xf, true); x = x > y ? x : y;
    y = (unsigned)__builtin_amdgcn_update_dpp(0, (int)x, 0x142, 0xa, 0xf, true); x = x > y ? x : y;
    y = (unsigned)__builtin_amdgcn_update_dpp(0, (int)x, 0x143, 0xc, 0xf, true); x = x > y ? x : y;
    return x;
}
__device__ __forceinline__ int dpp_red16_add(int x) {   // every lane: sum of its 16-group
    x += __builtin_amdgcn_update_dpp(0, x, 0xB1, 0xf, 0xf, true);  // quad_perm [1,0,3,2]
    x += __builtin_amdgcn_update_dpp(0, x, 0x4E, 0xf, 0xf, true);  // quad_perm [2,3,0,1]
    x += __builtin_amdgcn_update_dpp(0, x, 0x141, 0xf, 0xf, true); // row_half_mirror
    x += __builtin_amdgcn_update_dpp(0, x, 0x140, 0xf, 0xf, true); // row_mirror
    return x;
}
__device__ __forceinline__ unsigned dpp_red16_maxu(unsigned x) {
    unsigned y;
    y = (unsigned)__builtin_amdgcn_update_dpp(0, (int)x, 0xB1, 0xf, 0xf, true);  x = x > y ? x : y;
    y = (unsigned)__builtin_amdgcn_update_dpp(0, (int)x, 0x4E, 0xf, 0xf, true);  x = x > y ? x : y;
    y = (unsigned)__builtin_amdgcn_update_dpp(0, (int)x, 0x141, 0xf, 0xf, true); x = x > y ? x : y;
    y = (unsigned)__builtin_amdgcn_update_dpp(0, (int)x, 0x140, 0xf, 0xf, true); x = x > y ? x : y;
    return x;
}
// monotone float<->uint total-order keys (no NaNs in this kernel)
__device__ __forceinline__ unsigned fkey(float h) {
    unsigned s = __float_as_uint(h);
    return ((int)s < 0) ? ~s : (s | 0x80000000u);
}
__device__ __forceinline__ float ubf(unsigned u) {
    unsigned s = (u & 0x80000000u) ? (u & 0x7FFFFFFFu) : ~u;
    return __uint_as_float(s);
}

__global__ void __launch_bounds__(1024) wl_mega_k(const int* __restrict__ src,
                                                  const int* __restrict__ dstp,
                                                  const int* __restrict__ lab0,
                                                  const float* __restrict__ hw,
                                                  unsigned int* __restrict__ feats,
                                                  float* __restrict__ diag) {
    __shared__ union {
        unsigned int chunk[N * WPR];                // Phase A1: 128KB full bitmask
        struct {
            unsigned short nbr[CSR_SLOTS];          // Phase A2/B: 34816B CSR (self-read only)
            struct {                                // Phase B: rank arrays
                int hist[N];
                int scan[N];
                float grp[N];                       // slow-path ordered groups
                int flag[N];
                float grp2[N * GSTRIDE];            // fast-path groups, 36KB
            } pb;
        } s;
    } u;
    __shared__ int s_lab[N + 2];                    // +sentinel slot (=0)
    __shared__ unsigned int s_feats[N];
    __shared__ int s_wsum[16];
    __shared__ int s_kp[16];
    __shared__ unsigned long long s_mm64[16];       // packed (maxkey<<32)|minkey
    __shared__ int s_anytie;
    __shared__ int s_ovf;
    int b = blockIdx.x, t = threadIdx.x;
    int lane = t & 63, w = t >> 6;

    // ---- Phase A0: edge loads first (L3 latency overlaps LDS zero) ----
    const int* sg = src + (size_t)b * E;
    const int* dg_ = dstp + (size_t)b * E;
    int es[16], ed[16];
#pragma unroll
    for (int k = 0; k < 16; ++k) {                  // coalesced, 1 block/graph
        es[k] = sg[t + k * 1024];
        ed[k] = dg_[t + k * 1024];
    }
    int l0 = lab0[(size_t)b * N + t];
    float w0 = hw[0], w1 = hw[1];
    // zero 128KB bitmask while loads are in flight
#pragma unroll
    for (int k = 0; k < 8; ++k)
        ((uint4*)u.chunk)[t + k * 1024] = make_uint4(0, 0, 0, 0);
    s_lab[t] = l0;
    s_feats[t] = 0;
    if (t == 0) { s_lab[N] = 0; s_anytie = 0; s_ovf = 0; }
    __syncthreads();                                        // P0
    // init label bincount (labels < 16) via ballot
#pragma unroll
    for (int v = 0; v < 16; ++v) {
        unsigned long long m = __ballot(l0 == v);
        if (lane == v) {
            int c = __popcll(m);
            if (c) atomicAdd(&s_feats[v], (unsigned)c);
        }
    }

    // ---- Phase A1: bitmask scatter (swizzled), row -> r[8] ----
#pragma unroll
    for (int k = 0; k < 16; ++k) {
        int wlog = ed[k] >> 5;                      // logical word 0..31
        int g = wlog >> 2;                          // logical group 0..7
        int p = (g + es[k]) & 7;                    // swizzled slot
        atomicOr(&u.chunk[es[k] * WPR + p * 4 + (wlog & 3)], 1u << (ed[k] & 31));
    }
    __syncthreads();                                        // C2
    uint4 r[8];
    {
        const uint4* row4 = (const uint4*)(u.chunk + t * WPR);
#pragma unroll
        for (int g = 0; g < 8; ++g)
            r[g] = row4[(g + t) & 7];               // conflict-free (swizzled)
    }
    // NO C3: A1 (below) already separates this readback from the chunk-
    // aliasing writes (hist/flag init + pack); the window here touches only
    // registers and s_wsum/s_kp (outside the union).

    // ---- Phase A2: deg/alloc/K/CSR starts + pack ----
    int dg = 0;
#pragma unroll
    for (int k = 0; k < 8; ++k)
        dg += __popc(r[k].x) + __popc(r[k].y) + __popc(r[k].z) + __popc(r[k].w);
    int alloc = (dg + 1) & ~1;                      // even per-node CSR alloc

    int f = dpp_scan_add(alloc);                    // wave inclusive scan (VALU)
    unsigned kmw = dpp_scan_maxu((unsigned)dg);     // wave max deg (VALU)
    if (lane == 63) { s_wsum[w] = f; s_kp[w] = (int)kmw; }
    __syncthreads();                                        // A1
    // all-wave redundant combine: wave-exclusive base + block K, in registers
    float Kf;
    int start;
    {
        int vv = ((lane & 15) < w) ? s_wsum[lane & 15] : 0;
        vv = dpp_red16_add(vv);
        start = (f - alloc) + vv;                   // even => u32-aligned
        unsigned kk = dpp_red16_maxu((unsigned)s_kp[lane & 15]);
        Kf = (float)kk;
    }
    u.s.pb.hist[t] = 0;                             // aliases chunk: re-init
    u.s.pb.flag[t] = 0;

    // pack own row's set bits ONCE -> u16 list; pad odd deg with sentinel N
    {
        int idx = start;
#pragma unroll
        for (int k = 0; k < 8; ++k) {
            unsigned int wv[4] = { r[k].x, r[k].y, r[k].z, r[k].w };
#pragma unroll
            for (int c2 = 0; c2 < 4; ++c2) {
                unsigned int word = wv[c2];
                int bb = (k * 4 + c2) << 5;
                while (word) {
                    int j = __ffs(word) - 1;
                    word &= word - 1;
                    u.s.nbr[idx++] = (unsigned short)(bb + j);
                }
            }
        }
        if (dg & 1) u.s.nbr[idx] = (unsigned short)N;   // sentinel -> adds 0
    }
    // NO barrier: pw preload reads only this thread's own nbr bytes (same-
    // wave DS ops are serviced in order); fence stops compiler reordering.
    asm volatile("" ::: "memory");

    int vdeg = dg;
    int vpstart = start >> 1;
    int vpairs = alloc >> 1;
    int lab_reg = l0;
    const unsigned int* nbr32 = (const unsigned int*)u.s.nbr;
    // iteration-invariant pair-words -> registers; sentinel-pad to MAXP so
    // the hot loop needs NO predication (sentinel reads broadcast s_lab[N]=0)
    unsigned int pw[MAXP];
#pragma unroll
    for (int k = 0; k < MAXP; ++k)
        pw[k] = (k < vpairs) ? nbr32[vpstart + k] : SENT_PAIR;

    // ---- Phase B: 5 WL iterations ----
    int nfast = 0;                                  // fast-path feats counter
    for (int it = 0; it < NITER; ++it) {
        int ssum = 0;
#pragma unroll
        for (int k = 0; k < MAXP; ++k) {            // unconditional: 40 gathers
            unsigned int pr = pw[k];
            ssum += s_lab[pr & 0xFFFFu] + s_lab[pr >> 16];
        }
        for (int k = MAXP; k < vpairs; ++k) {       // rare high-deg fallback
            unsigned int pr = nbr32[vpstart + k];
            ssum += s_lab[pr & 0xFFFFu] + s_lab[pr >> 16];
        }
        float t1 = __fmul_rn(__fmul_rn(Kf, w0), (float)lab_reg);
        float t2 = __fmul_rn(w1, __fsub_rn(__fadd_rn((float)ssum, (float)vdeg), Kf));
        float h  = __fadd_rn(t1, t2);

        // wave min/max via DPP max-scan on biased keys (VALU, no DS)
        unsigned uk = fkey(h);
        unsigned kx = dpp_scan_maxu(uk);
        unsigned kn = dpp_scan_maxu(~uk);
        if (lane == 63)
            s_mm64[w] = ((unsigned long long)kx << 32) | kn;  // one b64 store
        __syncthreads();                                    // B1
        // all-wave redundant combine -> registers (one b64 load)
        float fmn, span;
        {
            unsigned long long mm = s_mm64[lane & 15];
            unsigned a = dpp_red16_maxu((unsigned)mm);      // max of ~key = min
            unsigned cx = dpp_red16_maxu((unsigned)(mm >> 32));
            fmn = ubf(~a);
            span = ubf(cx) - fmn;
        }
        float scale = (span > 0.f) ? (1023.0f / span) : 0.f;
        int bucket = min((int)((h - fmn) * scale), 1023);   // order-preserving
        int off_in = atomicAdd(&u.s.pb.hist[bucket], 1);
        if (off_in < CAP) u.s.pb.grp2[bucket * GSTRIDE + off_in] = h; // B3 covers
        else s_ovf = 1;                                               // rare
        __syncthreads();                                    // B3

        int ovf = s_ovf;                            // uniform post-B3
        int cnt = u.s.pb.hist[bucket];              // final bucket count (reg)
        int c_in = 0, eq = 0;
        if (!ovf) {                                 // CAP unconditional reads,
#pragma unroll                                      // predicated compares
            for (int j = 0; j < CAP; ++j) {
                float g = u.s.pb.grp2[bucket * GSTRIDE + j];
                if (j < cnt) { c_in += (g < h); eq += (g == h); }
            }
        }
        f = dpp_scan_add(u.s.pb.hist[t]);           // WAVE-inclusive scan
        u.s.pb.scan[t] = f;                         // lane63 entries = wave totals
        __syncthreads();                                    // B4' (merged B4+B6)

        // block-inclusive at bucket: scan[bucket] + prefix of wave totals
        int sb = u.s.pb.scan[bucket];
        {
            int wb = bucket >> 6;
#pragma unroll
            for (int w2 = 0; w2 < 15; ++w2) {       // broadcast reads (same addr)
                int wt = u.s.pb.scan[w2 * 64 + 63];
                if (w2 < wb) sb += wt;
            }
        }
        u.s.pb.hist[t] = 0;             // post-B4': ordered vs cnt latches
        if (t == 0) s_ovf = 0;          // post-B4': ordered vs ovf latches
        int cr;
        if (!ovf) {
            cr = (sb - cnt) + c_in;     // dense rank iff no ties
        } else {                        // slow path: scan-ordered groups
            int bs = sb - cnt;
            u.s.pb.grp[bs + off_in] = h;
            __syncthreads();                                // B7 (rare)
            cr = bs;
            eq = 0;
            for (int k = bs; k < bs + cnt; ++k) {
                float g = u.s.pb.grp[k];
                cr += (g < h);
                eq += (g == h);
            }
        }
        if (eq > 1) s_anytie = it + 1;  // sentinel: stale iters self-invalidate
        s_lab[t] = cr;                  // optimistic fast-path rank
        __syncthreads();                                    // B9
        if (s_anytie == it + 1) {       // rare: dense-rank repair pass
            u.s.pb.flag[cr] = 1;        // class start (same class -> same cr)
            __syncthreads();                                // T1
            int f2 = dpp_scan_add(u.s.pb.flag[t]);  // WAVE-inclusive
            u.s.pb.scan[t] = f2;
            __syncthreads();                                // T2 (merged)
            int sc = u.s.pb.scan[cr];
            {
                int wb2 = cr >> 6;
#pragma unroll
                for (int w2 = 0; w2 < 15; ++w2) {
                    int wt = u.s.pb.scan[w2 * 64 + 63];
                    if (w2 < wb2) sc += wt;
                }
            }
            u.s.pb.flag[t] = 0;         // own flag consumed pre-T2
            int rank = sc - 1;
            s_lab[t] = rank;
            lab_reg = rank;
            atomicAdd(&s_feats[rank], 1u);
            __syncthreads();                                // T5: labels visible
        } else {
            lab_reg = cr;
            ++nfast;                    // permutation => every bin +1
        }
    }

    // ---- Phase C: feats out + fused diag[b] (int exact) ----
    unsigned int fv = s_feats[t] + (unsigned)nfast;
    feats[(size_t)b * N + t] = fv;
    int sq = dpp_scan_add((int)(fv * fv));
    if (lane == 63) s_wsum[w] = sq;
    __syncthreads();
    if (t == 0) {
        int tot = 0;
#pragma unroll
        for (int k = 0; k < 16; ++k) tot += s_wsum[k];
        diag[b] = (float)tot;
    }
}

// gram+normalize fused: one block per row i; f_i staged in LDS; int dots
// exact. 1024 threads, 16 waves x 4 j's each; DPP scan-sum, lane63 stores.
__global__ void __launch_bounds__(1024) gram_k(const unsigned int* __restrict__ feats,
                                               const float* __restrict__ diag,
                                               float* __restrict__ out) {
    __shared__ unsigned int s_fi[N];
    int i = blockIdx.x, t = threadIdx.x;
    int lane = t & 63, w = t >> 6;
    if (t < 256)
        ((uint4*)s_fi)[t] = ((const uint4*)(feats + (size_t)i * N))[t];
    __syncthreads();
    float di = diag[i];
#pragma unroll
    for (int jj = 0; jj < 4; ++jj) {
        int j = w * 4 + jj;
        const uint4* fj = (const uint4*)(feats + (size_t)j * N);
        const uint4* fi = (const uint4*)s_fi;
        int s = 0;
#pragma unroll
        for (int k = 0; k < 4; ++k) {
            uint4 vb = fj[lane + k * 64];
            uint4 va = fi[lane + k * 64];
            s += (int)(va.x * vb.x) + (int)(va.y * vb.y)
               + (int)(va.z * vb.z) + (int)(va.w * vb.w);
        }
        s = dpp_scan_add(s);
        if (lane == 63) out[i * B + j] = (float)s / sqrtf(di * diag[j]);
    }
}

extern "C" void kernel_launch(void* const* d_in, const int* in_sizes, int n_in,
                              void* d_out, int out_size, void* d_ws, size_t ws_size,
                              hipStream_t stream) {
    const int*   esrc = (const int*)d_in[0];
    const int*   edst = (const int*)d_in[1];
    const int*   lab0 = (const int*)d_in[2];
    const float* hw   = (const float*)d_in[3];

    char* ws = (char*)d_ws;
    unsigned int* feats = (unsigned int*)(ws + FEATS_OFF);
    float*        diag  = (float*)(ws + DIAG_OFF);

    wl_mega_k<<<B, 1024, 0, stream>>>(esrc, edst, lab0, hw, feats, diag);
    gram_k<<<B, 1024, 0, stream>>>(feats, diag, (float*)d_out);
}